// Round 10
// baseline (1513.952 us; speedup 1.0000x reference)
//
#include <hip/hip_runtime.h>
#include <hip/hip_fp16.h>

typedef _Float16 half_t;
typedef _Float16 half8 __attribute__((ext_vector_type(8)));
typedef float floatx4 __attribute__((ext_vector_type(4)));
typedef int   int4v  __attribute__((ext_vector_type(4)));

// ---- sizes ----
#define T_STEPS 300
#define NMB     1024                 // N*M batch
#define BS      16                   // steps per staged block
#define NBLK    19                   // ceil(300/16)
#define RPW     8                    // batch rows per WG

// ws layout (bytes)
#define XT_OFF   0ULL
#define XT_BYTES ((unsigned long long)(T_STEPS*NMB + 16)*64*2)
#define HS0_OFF  (XT_OFF + XT_BYTES)
#define HS0_BYTES ((unsigned long long)(T_STEPS*NMB + 16)*128*2)
#define WCH_OFF  (HS0_OFF + HS0_BYTES)        // wcomb as f16 [512][64]
#define WCH_BYTES (512ULL*64*2)
#define BC_OFF   (WCH_OFF + WCH_BYTES)        // biasc f32 [512]
#define BC_BYTES (512ULL*4)
#define FL_OFF   (BC_OFF + BC_BYTES)          // flags int[128]

// L_hat = -D^-1/2 A D^-1/2 for the hardcoded 15-node skeleton (row=dst, col=src)
#define S2 0.70710678118654752f
#define QH 0.5f
#define UU 0.40824829046386302f
#define TH 0.33333333333333333f
__constant__ float LHAT[225] = {
  0,0,-S2,0,0,0,0,0,0,0,0,0,0,0,0,
  0,0,0,-S2,0,0,0,0,0,0,0,0,0,0,0,
  -S2,0,0,0,-QH,0,0,0,0,0,0,0,0,0,0,
  0,-S2,0,0,0,-QH,0,0,0,0,0,0,0,0,0,
  0,0,-QH,0,0,0,0,0,0,0,0,0,0,0,-UU,
  0,0,0,-QH,0,0,0,0,0,0,0,0,0,0,-UU,
  0,0,0,0,0,0,0,0,-S2,0,0,0,0,0,0,
  0,0,0,0,0,0,0,0,0,-S2,0,0,0,0,0,
  0,0,0,0,0,0,-S2,0,0,0,-QH,0,0,0,0,
  0,0,0,0,0,0,0,-S2,0,0,0,-QH,0,0,0,
  0,0,0,0,0,0,0,0,-QH,0,0,0,0,-UU,0,
  0,0,0,0,0,0,0,0,0,-QH,0,0,0,-UU,0,
  0,0,0,0,0,0,0,0,0,0,0,0,0,0,0,
  0,0,0,0,0,0,0,0,0,0,-UU,-UU,0,0,0,
  0,0,0,0,-UU,-UU,0,0,0,0,0,0,0,-TH,0
};

// Fast gate math: v_exp_f32 + v_rcp_f32 (approx, ~1 ulp).
__device__ __forceinline__ float frcp(float x)  { return __builtin_amdgcn_rcpf(x); }
__device__ __forceinline__ float fsig(float x)  { return frcp(1.f + __expf(-x)); }
__device__ __forceinline__ float ftanh(float x) { return 2.f*frcp(1.f + __expf(-2.f*x)) - 1.f; }

__device__ __forceinline__ half8 load_w8(const float* p) {
  const float4* q = (const float4*)p;
  float4 a = q[0], b = q[1];
  half8 f;
  f[0]=(half_t)a.x; f[1]=(half_t)a.y; f[2]=(half_t)a.z; f[3]=(half_t)a.w;
  f[4]=(half_t)b.x; f[5]=(half_t)b.y; f[6]=(half_t)b.z; f[7]=(half_t)b.w;
  return f;
}

// Force true register residency of weight fragments (kills per-step remat).
__device__ __forceinline__ void pin(half8& f) {
  int4v t = __builtin_bit_cast(int4v, f);
  asm volatile("" : "+v"(t));
  f = __builtin_bit_cast(half8, t);
}

// Agent-scope acquire spin (consumer waits for producer block flag).
__device__ __forceinline__ void waitge(int* f, int v) {
  while (__hip_atomic_load(f, __ATOMIC_ACQUIRE, __HIP_MEMORY_SCOPE_AGENT) < v)
    __builtin_amdgcn_s_sleep(8);
}

// ---- K0: fold ChebConv into layer-0 input projection + zero sync flags
__global__ void k_prep(const float* __restrict__ w0, const float* __restrict__ w1,
                       const float* __restrict__ cb, const float* __restrict__ wih0,
                       const float* __restrict__ bih0, const float* __restrict__ bhh0,
                       half_t* __restrict__ wcomb_h, float* __restrict__ biasc,
                       int* __restrict__ flags) {
  const int n = threadIdx.x; // 512 threads, 1 block
  if (n < 128) flags[n] = 0;
  float wrow[45];
  #pragma unroll
  for (int i=0;i<45;i++) wrow[i] = wih0[n*45+i];
  float P[45];
  #pragma unroll
  for (int i=0;i<15;i++)
    #pragma unroll
    for (int c=0;c<3;c++) {
      float s = 0.f;
      #pragma unroll
      for (int cp=0;cp<3;cp++) s += wrow[i*3+cp]*w1[cp*3+c];
      P[i*3+c] = s;
    }
  #pragma unroll
  for (int j=0;j<15;j++)
    #pragma unroll
    for (int c=0;c<3;c++) {
      float s = 0.f;
      #pragma unroll
      for (int cp=0;cp<3;cp++) s += wrow[j*3+cp]*w0[cp*3+c];
      #pragma unroll
      for (int i=0;i<15;i++) s += LHAT[i*15+j]*P[i*3+c];
      wcomb_h[n*64 + j*3+c] = (half_t)s;
    }
  for (int k=45;k<64;k++) wcomb_h[n*64+k] = (half_t)0.f;
  float b = bih0[n] + bhh0[n];
  #pragma unroll
  for (int i=0;i<15;i++)
    #pragma unroll
    for (int cp=0;cp<3;cp++) b += wrow[i*3+cp]*cb[cp];
  biasc[n] = b;
}

// ---- K0b: x1 [N,C,T,V,M] fp32 -> xt [t*1024+nm][64] fp16 (features v*3+c, 45 valid)
__global__ void k_xpose(const float* __restrict__ x1, half_t* __restrict__ xt) {
  const int id = blockIdx.x*256 + threadIdx.x;   // exactly 512*3*300*15 = 6,912,000
  const int v  = id % 15;
  const int r1 = id / 15;
  const int t  = r1 % 300;
  const int r2 = r1 / 300;
  const int c  = r2 % 3;
  const int n  = r2 / 3;
  const float2 f = ((const float2*)x1)[id];      // m=0,1 pair, coalesced
  const size_t row = (size_t)t*NMB + n*2;
  xt[row*64     + v*3 + c] = (half_t)f.x;
  xt[(row+1)*64 + v*3 + c] = (half_t)f.y;
}

// ---- Pipelined 2-layer LSTM: 256 WGs x 512 threads, 1 WG/CU.
// WGs 0..127 run layer-0 on rows wg*8..wg*8+7; WGs 128..255 run layer-1 on the same
// rows, lagging by >=2 staged blocks, synced via agent-scope flags. Each wave: 4 N-tiles
// (gcol = nt*128 + wave*16 + l16). A-rows replicated as l16&7; lane (quad,l16) owns
// cells j=0,1 at row rbase+j = 4*(quad&1)+2*(quad>>1)+j via C-comps c0+j.
__launch_bounds__(512, 2)
__global__ void k_pipe(const half_t* __restrict__ xt, const half_t* __restrict__ wch,
                       const float* __restrict__ biasc, const float* __restrict__ whh0,
                       half_t* __restrict__ hs0,
                       const float* __restrict__ wih1, const float* __restrict__ whh1,
                       const float* __restrict__ bih1, const float* __restrict__ bhh1,
                       const float* __restrict__ fcw, const float* __restrict__ fcb,
                       float* __restrict__ out, int* __restrict__ flags) {
  __shared__ __align__(16) char smem[80256];
  const int tid = threadIdx.x;
  const int wave = tid>>6, lane = tid&63, quad = lane>>4, l16 = lane&15;
  const int rbase = 4*(quad&1) + 2*(quad>>1);
  const int c0 = 2*(quad>>1);
  const int arow = l16 & 7;

  if (blockIdx.x < 128) {
    // ================= producer: layer-0 =================
    const int wg = blockIdx.x, nm0 = wg*RPW;
    half_t* xs = (half_t*)smem;                        // [2][BS][8][80]
    half_t* hr = (half_t*)(smem + 2*BS*RPW*80*2);      // [16][8][144]
    for (int i=tid; i<RPW*144; i+=512) hr[15*RPW*144 + i] = (half_t)0.f;

    half8 whhF[4][4]; half8 wcF[4][2]; float bias[4];
    #pragma unroll
    for (int nt=0; nt<4; nt++) {
      const int gcol = nt*128 + wave*16 + l16;
      #pragma unroll
      for (int kc=0; kc<4; kc++) { whhF[nt][kc] = load_w8(whh0 + gcol*128 + kc*32 + quad*8); pin(whhF[nt][kc]); }
      #pragma unroll
      for (int kc=0; kc<2; kc++) { wcF[nt][kc] = *(const half8*)(wch + gcol*64 + kc*32 + quad*8); pin(wcF[nt][kc]); }
      bias[nt] = biasc[gcol];
    }
    float cst[2] = {0.f,0.f};

    // staging: 512 threads x 32B = one block (16 x 8 x 64 halfs)
    const int sS = tid>>5, sR = (tid>>2)&7, sC = (tid&3)*16;
    float4 ld0, ld1;
    { const half_t* src = xt + ((size_t)sS*NMB + nm0 + sR)*64 + sC;
      ld0 = *(const float4*)src; ld1 = *(const float4*)(src+8); }
    *(half8*)&xs[((0*BS+sS)*RPW+sR)*80 + sC]     = __builtin_bit_cast(half8, ld0);
    *(half8*)&xs[((0*BS+sS)*RPW+sR)*80 + sC + 8] = __builtin_bit_cast(half8, ld1);
    __syncthreads();

    // peel: gx for t=0
    float gx[8];
    {
      half8 xA[2];
      #pragma unroll
      for (int kc=0; kc<2; kc++) xA[kc] = *(const half8*)&xs[(0*RPW+arow)*80 + kc*32 + quad*8];
      #pragma unroll
      for (int nt=0; nt<4; nt++) {
        floatx4 a = {bias[nt],bias[nt],bias[nt],bias[nt]};
        a = __builtin_amdgcn_mfma_f32_16x16x32_f16(xA[0], wcF[nt][0], a, 0,0,0);
        a = __builtin_amdgcn_mfma_f32_16x16x32_f16(xA[1], wcF[nt][1], a, 0,0,0);
        gx[nt*2+0] = a[c0]; gx[nt*2+1] = a[c0+1];
      }
    }

    for (int b=0; b<NBLK; b++) {
      const int bs = b*BS, buf = b&1;
      const int cnt = (T_STEPS - bs < BS) ? (T_STEPS - bs) : BS;
      if (b+1 < NBLK) {
        int tt = bs + BS + sS; if (tt > 299) tt = 299;
        const half_t* src = xt + ((size_t)tt*NMB + nm0 + sR)*64 + sC;
        ld0 = *(const float4*)src; ld1 = *(const float4*)(src+8);
      }
      for (int s=0; s<cnt; s++) {
        const int t = bs + s;
        if (s == 1 && b+1 < NBLK) {
          *(half8*)&xs[(((buf^1)*BS+sS)*RPW+sR)*80 + sC]     = __builtin_bit_cast(half8, ld0);
          *(half8*)&xs[(((buf^1)*BS+sS)*RPW+sR)*80 + sC + 8] = __builtin_bit_cast(half8, ld1);
        }
        // xproj for step t+1
        float gxn[8];
        {
          const half_t* xrow = (s+1 < cnt) ? &xs[((buf*BS+s+1)*RPW+arow)*80]
                                           : &xs[(((buf^1)*BS+0)*RPW+arow)*80];  // unused at t==299
          half8 xA[2];
          #pragma unroll
          for (int kc=0; kc<2; kc++) xA[kc] = *(const half8*)(xrow + kc*32 + quad*8);
          #pragma unroll
          for (int nt=0; nt<4; nt++) {
            floatx4 a = {bias[nt],bias[nt],bias[nt],bias[nt]};
            a = __builtin_amdgcn_mfma_f32_16x16x32_f16(xA[0], wcF[nt][0], a, 0,0,0);
            a = __builtin_amdgcn_mfma_f32_16x16x32_f16(xA[1], wcF[nt][1], a, 0,0,0);
            gxn[nt*2+0] = a[c0]; gxn[nt*2+1] = a[c0+1];
          }
        }
        // recurrent h-chain
        half8 hA[4];
        const half_t* hrow = &hr[(((t+15)&15)*RPW+arow)*144];
        #pragma unroll
        for (int kc=0; kc<4; kc++) hA[kc] = *(const half8*)(hrow + kc*32 + quad*8);
        floatx4 ah[4];
        #pragma unroll
        for (int nt=0; nt<4; nt++) {
          floatx4 a = {0.f,0.f,0.f,0.f};
          #pragma unroll
          for (int kc=0; kc<4; kc++)
            a = __builtin_amdgcn_mfma_f32_16x16x32_f16(hA[kc], whhF[nt][kc], a, 0,0,0);
          ah[nt] = a;
        }
        #pragma unroll
        for (int j=0; j<2; j++) {
          const float gi = ah[0][c0+j] + gx[0+j];
          const float gf = ah[1][c0+j] + gx[2+j];
          const float gg = ah[2][c0+j] + gx[4+j];
          const float go = ah[3][c0+j] + gx[6+j];
          cst[j] = fsig(gf)*cst[j] + fsig(gi)*ftanh(gg);
          hr[((t&15)*RPW + rbase+j)*144 + wave*16 + l16] = (half_t)(fsig(go)*ftanh(cst[j]));
        }
        #pragma unroll
        for (int nt=0; nt<8; nt++) gx[nt] = gxn[nt];
        __syncthreads();
      }
      // bulk store this block's h to hs0 (64B per thread)
      {
        const int hS = tid>>5, hR = (tid>>2)&7, hC = (tid&3)*32;
        if (hS < cnt) {
          const half_t* srcr = &hr[(((bs+hS)&15)*RPW+hR)*144 + hC];
          half_t* dst = hs0 + ((size_t)(bs+hS)*NMB + nm0 + hR)*128 + hC;
          #pragma unroll
          for (int p=0; p<4; p++) *(half8*)(dst + p*8) = *(const half8*)(srcr + p*8);
        }
      }
      __threadfence();              // write-back for cross-XCD visibility
      __syncthreads();
      if (tid == 0)
        __hip_atomic_store(&flags[wg], b+1, __ATOMIC_RELEASE, __HIP_MEMORY_SCOPE_AGENT);
    }
  } else {
    // ================= consumer: layer-1 + FC + softmax =================
    const int wg = blockIdx.x - 128, nm0 = wg*RPW;
    half_t* xs = (half_t*)smem;                            // [2][BS][8][144]
    half_t* h2 = (half_t*)(smem + 2*BS*RPW*144*2);         // [2][8][144]
    float* logits = (float*)(smem + 2*BS*RPW*144*2 + 2*RPW*144*2);
    for (int i=tid; i<RPW*144; i+=512) h2[i] = (half_t)0.f;

    half8 wxF[4][4], whF[4][4]; float bias[4];
    #pragma unroll
    for (int nt=0; nt<4; nt++) {
      const int gcol = nt*128 + wave*16 + l16;
      #pragma unroll
      for (int kc=0; kc<4; kc++) {
        wxF[nt][kc] = load_w8(wih1 + gcol*128 + kc*32 + quad*8); pin(wxF[nt][kc]);
        whF[nt][kc] = load_w8(whh1 + gcol*128 + kc*32 + quad*8); pin(whF[nt][kc]);
      }
      bias[nt] = bih1[gcol] + bhh1[gcol];
    }
    float cst[2] = {0.f,0.f};

    // staging: 512 threads x 64B = one block (16 x 8 x 128 halfs)
    const int sS = tid>>5, sR = (tid>>2)&7, sC = (tid&3)*32;
    float4 ld[4];
    waitge(&flags[wg], 1);
    { const half_t* src = hs0 + ((size_t)sS*NMB + nm0 + sR)*128 + sC;
      #pragma unroll
      for (int p=0; p<4; p++) ld[p] = *(const float4*)(src + p*8); }
    #pragma unroll
    for (int p=0; p<4; p++) *(half8*)&xs[((0*BS+sS)*RPW+sR)*144 + sC + p*8] = __builtin_bit_cast(half8, ld[p]);
    __syncthreads();

    // peel: gx for t=0
    float gx[8];
    {
      half8 xA[4];
      #pragma unroll
      for (int kc=0; kc<4; kc++) xA[kc] = *(const half8*)&xs[(0*RPW+arow)*144 + kc*32 + quad*8];
      #pragma unroll
      for (int nt=0; nt<4; nt++) {
        floatx4 a = {bias[nt],bias[nt],bias[nt],bias[nt]};
        #pragma unroll
        for (int kc=0; kc<4; kc++)
          a = __builtin_amdgcn_mfma_f32_16x16x32_f16(xA[kc], wxF[nt][kc], a, 0,0,0);
        gx[nt*2+0] = a[c0]; gx[nt*2+1] = a[c0+1];
      }
    }

    for (int b=0; b<NBLK; b++) {
      const int bs = b*BS, buf = b&1;
      const int cnt = (T_STEPS - bs < BS) ? (T_STEPS - bs) : BS;
      if (b+1 < NBLK) {
        waitge(&flags[wg], b+2);
        int tt = bs + BS + sS; if (tt > 299) tt = 299;
        const half_t* src = hs0 + ((size_t)tt*NMB + nm0 + sR)*128 + sC;
        #pragma unroll
        for (int p=0; p<4; p++) ld[p] = *(const float4*)(src + p*8);
      }
      for (int s=0; s<cnt; s++) {
        const int t = bs + s;
        if (s == 1 && b+1 < NBLK) {
          #pragma unroll
          for (int p=0; p<4; p++) *(half8*)&xs[(((buf^1)*BS+sS)*RPW+sR)*144 + sC + p*8] = __builtin_bit_cast(half8, ld[p]);
        }
        // xproj for step t+1
        float gxn[8];
        {
          const half_t* xrow = (s+1 < cnt) ? &xs[((buf*BS+s+1)*RPW+arow)*144]
                                           : &xs[(((buf^1)*BS+0)*RPW+arow)*144];
          half8 xA[4];
          #pragma unroll
          for (int kc=0; kc<4; kc++) xA[kc] = *(const half8*)(xrow + kc*32 + quad*8);
          #pragma unroll
          for (int nt=0; nt<4; nt++) {
            floatx4 a = {bias[nt],bias[nt],bias[nt],bias[nt]};
            #pragma unroll
            for (int kc=0; kc<4; kc++)
              a = __builtin_amdgcn_mfma_f32_16x16x32_f16(xA[kc], wxF[nt][kc], a, 0,0,0);
            gxn[nt*2+0] = a[c0]; gxn[nt*2+1] = a[c0+1];
          }
        }
        // recurrent h-chain
        half8 hA[4];
        const half_t* hrow = &h2[((t&1)*RPW+arow)*144];
        #pragma unroll
        for (int kc=0; kc<4; kc++) hA[kc] = *(const half8*)(hrow + kc*32 + quad*8);
        floatx4 ah[4];
        #pragma unroll
        for (int nt=0; nt<4; nt++) {
          floatx4 a = {0.f,0.f,0.f,0.f};
          #pragma unroll
          for (int kc=0; kc<4; kc++)
            a = __builtin_amdgcn_mfma_f32_16x16x32_f16(hA[kc], whF[nt][kc], a, 0,0,0);
          ah[nt] = a;
        }
        #pragma unroll
        for (int j=0; j<2; j++) {
          const float gi = ah[0][c0+j] + gx[0+j];
          const float gf = ah[1][c0+j] + gx[2+j];
          const float gg = ah[2][c0+j] + gx[4+j];
          const float go = ah[3][c0+j] + gx[6+j];
          cst[j] = fsig(gf)*cst[j] + fsig(gi)*ftanh(gg);
          h2[(((t+1)&1)*RPW + rbase+j)*144 + wave*16 + l16] = (half_t)(fsig(go)*ftanh(cst[j]));
        }
        #pragma unroll
        for (int nt=0; nt<8; nt++) gx[nt] = gxn[nt];
        __syncthreads();
      }
    }

    // ---- FC (60 classes) + softmax; h1[299] in h2 buffer 0 (t=299 wrote (299+1)&1=0)
    if (tid < 480) {
      const int r2 = tid/60, cls = tid%60;
      float s = fcb[cls];
      for (int k2=0; k2<128; k2++) s += (float)h2[(0*RPW+r2)*144 + k2] * fcw[cls*128+k2];
      logits[r2*60+cls] = s;
    }
    __syncthreads();
    if (tid < 8) {
      float m = -1e30f;
      for (int j=0; j<60; j++) m = fmaxf(m, logits[tid*60+j]);
      float s = 0.f;
      for (int j=0; j<60; j++) s += __expf(logits[tid*60+j]-m);
      const float inv = frcp(s);
      for (int j=0; j<60; j++) out[(nm0+tid)*60+j] = __expf(logits[tid*60+j]-m)*inv;
    }
  }
}

extern "C" void kernel_launch(void* const* d_in, const int* in_sizes, int n_in,
                              void* d_out, int out_size, void* d_ws, size_t ws_size,
                              hipStream_t stream) {
  const float* x1      = (const float*)d_in[0];
  const float* cheb_w0 = (const float*)d_in[2];
  const float* cheb_w1 = (const float*)d_in[3];
  const float* cheb_b  = (const float*)d_in[4];
  const float* wih0    = (const float*)d_in[5];
  const float* whh0    = (const float*)d_in[6];
  const float* bih0    = (const float*)d_in[7];
  const float* bhh0    = (const float*)d_in[8];
  const float* wih1    = (const float*)d_in[9];
  const float* whh1    = (const float*)d_in[10];
  const float* bih1    = (const float*)d_in[11];
  const float* bhh1    = (const float*)d_in[12];
  const float* fc_w    = (const float*)d_in[13];
  const float* fc_b    = (const float*)d_in[14];

  char* ws = (char*)d_ws;
  half_t* xt    = (half_t*)(ws + XT_OFF);
  half_t* hs0   = (half_t*)(ws + HS0_OFF);
  half_t* wch   = (half_t*)(ws + WCH_OFF);
  float*  biasc = (float*)(ws + BC_OFF);
  int*    flags = (int*)(ws + FL_OFF);

  k_prep <<<dim3(1),     dim3(512), 0, stream>>>(cheb_w0, cheb_w1, cheb_b, wih0, bih0, bhh0, wch, biasc, flags);
  k_xpose<<<dim3(27000), dim3(256), 0, stream>>>(x1, xt);
  k_pipe <<<dim3(256),   dim3(512), 0, stream>>>(xt, wch, biasc, whh0, hs0,
                                                 wih1, whh1, bih1, bhh1, fc_w, fc_b,
                                                 (float*)d_out, flags);
}

// Round 11
// 562.937 us; speedup vs baseline: 2.6894x; 2.6894x over previous
//
#include <hip/hip_runtime.h>
#include <hip/hip_fp16.h>

typedef _Float16 half_t;
typedef _Float16 half8 __attribute__((ext_vector_type(8)));
typedef float floatx4 __attribute__((ext_vector_type(4)));
typedef int   int4v  __attribute__((ext_vector_type(4)));

// ---- sizes ----
#define T_STEPS 300
#define NMB     1024                 // N*M batch
#define BS      16                   // steps per staged block
#define NBLK    19                   // ceil(300/16)

// ws layout (bytes)
#define XT_OFF   0ULL
#define XT_BYTES ((unsigned long long)(T_STEPS*NMB + 16)*64*2)
#define HS0_OFF  (XT_OFF + XT_BYTES)
#define HS0_BYTES ((unsigned long long)(T_STEPS*NMB + 16)*128*2)
#define WCH_OFF  (HS0_OFF + HS0_BYTES)        // wcomb as f16 [512][64]
#define WCH_BYTES (512ULL*64*2)
#define BC_OFF   (WCH_OFF + WCH_BYTES)        // biasc f32 [512]

// L_hat = -D^-1/2 A D^-1/2 for the hardcoded 15-node skeleton (row=dst, col=src)
#define S2 0.70710678118654752f
#define QH 0.5f
#define UU 0.40824829046386302f
#define TH 0.33333333333333333f
__constant__ float LHAT[225] = {
  0,0,-S2,0,0,0,0,0,0,0,0,0,0,0,0,
  0,0,0,-S2,0,0,0,0,0,0,0,0,0,0,0,
  -S2,0,0,0,-QH,0,0,0,0,0,0,0,0,0,0,
  0,-S2,0,0,0,-QH,0,0,0,0,0,0,0,0,0,
  0,0,-QH,0,0,0,0,0,0,0,0,0,0,0,-UU,
  0,0,0,-QH,0,0,0,0,0,0,0,0,0,0,-UU,
  0,0,0,0,0,0,0,0,-S2,0,0,0,0,0,0,
  0,0,0,0,0,0,0,0,0,-S2,0,0,0,0,0,
  0,0,0,0,0,0,-S2,0,0,0,-QH,0,0,0,0,
  0,0,0,0,0,0,0,-S2,0,0,0,-QH,0,0,0,
  0,0,0,0,0,0,0,0,-QH,0,0,0,0,-UU,0,
  0,0,0,0,0,0,0,0,0,-QH,0,0,0,-UU,0,
  0,0,0,0,0,0,0,0,0,0,0,0,0,0,0,
  0,0,0,0,0,0,0,0,0,0,-UU,-UU,0,0,0,
  0,0,0,0,-UU,-UU,0,0,0,0,0,0,0,-TH,0
};

// Fast gate math: v_exp_f32 + v_rcp_f32 (approx, ~1 ulp).
__device__ __forceinline__ float frcp(float x)  { return __builtin_amdgcn_rcpf(x); }
__device__ __forceinline__ float fsig(float x)  { return frcp(1.f + __expf(-x)); }
__device__ __forceinline__ float ftanh(float x) { return 2.f*frcp(1.f + __expf(-2.f*x)) - 1.f; }

__device__ __forceinline__ half8 load_w8(const float* p) {
  const float4* q = (const float4*)p;
  float4 a = q[0], b = q[1];
  half8 f;
  f[0]=(half_t)a.x; f[1]=(half_t)a.y; f[2]=(half_t)a.z; f[3]=(half_t)a.w;
  f[4]=(half_t)b.x; f[5]=(half_t)b.y; f[6]=(half_t)b.z; f[7]=(half_t)b.w;
  return f;
}

// Force true register residency of weight fragments (kills per-step remat).
__device__ __forceinline__ void pin(half8& f) {
  int4v t = __builtin_bit_cast(int4v, f);
  asm volatile("" : "+v"(t));
  f = __builtin_bit_cast(half8, t);
}

// ---- K0: fold ChebConv into layer-0 input projection: wcomb_h f16[512][64], biasc[512]
__global__ void k_prep(const float* __restrict__ w0, const float* __restrict__ w1,
                       const float* __restrict__ cb, const float* __restrict__ wih0,
                       const float* __restrict__ bih0, const float* __restrict__ bhh0,
                       half_t* __restrict__ wcomb_h, float* __restrict__ biasc) {
  const int n = threadIdx.x; // 512 threads, 1 block
  float wrow[45];
  #pragma unroll
  for (int i=0;i<45;i++) wrow[i] = wih0[n*45+i];
  float P[45];
  #pragma unroll
  for (int i=0;i<15;i++)
    #pragma unroll
    for (int c=0;c<3;c++) {
      float s = 0.f;
      #pragma unroll
      for (int cp=0;cp<3;cp++) s += wrow[i*3+cp]*w1[cp*3+c];
      P[i*3+c] = s;
    }
  #pragma unroll
  for (int j=0;j<15;j++)
    #pragma unroll
    for (int c=0;c<3;c++) {
      float s = 0.f;
      #pragma unroll
      for (int cp=0;cp<3;cp++) s += wrow[j*3+cp]*w0[cp*3+c];
      #pragma unroll
      for (int i=0;i<15;i++) s += LHAT[i*15+j]*P[i*3+c];
      wcomb_h[n*64 + j*3+c] = (half_t)s;
    }
  for (int k=45;k<64;k++) wcomb_h[n*64+k] = (half_t)0.f;
  float b = bih0[n] + bhh0[n];
  #pragma unroll
  for (int i=0;i<15;i++)
    #pragma unroll
    for (int cp=0;cp<3;cp++) b += wrow[i*3+cp]*cb[cp];
  biasc[n] = b;
}

// ---- K0b: x1 [N,C,T,V,M] fp32 -> xt [t*1024+nm][64] fp16 (features v*3+c, 45 valid)
__global__ void k_xpose(const float* __restrict__ x1, half_t* __restrict__ xt) {
  const int id = blockIdx.x*256 + threadIdx.x;   // exactly 512*3*300*15 = 6,912,000
  const int v  = id % 15;
  const int r1 = id / 15;
  const int t  = r1 % 300;
  const int r2 = r1 / 300;
  const int c  = r2 % 3;
  const int n  = r2 / 3;
  const float2 f = ((const float2*)x1)[id];      // m=0,1 pair, coalesced
  const size_t row = (size_t)t*NMB + n*2;
  xt[row*64     + v*3 + c] = (half_t)f.x;
  xt[(row+1)*64 + v*3 + c] = (half_t)f.y;
}

// ---- KA: layer-0 LSTM. 256 WGs x 512 threads; 4 batch rows/WG; 2 blocks/CU.
// x staged to LDS in 16-step blocks; h in a 16-deep LDS ring, bulk-stored per block.
// xproj pipelined one step ahead as a full floatx4 (bias in C-init); the h-chain
// initializes its MFMA accumulator from it directly -> no zero-init movs, no gate
// recombine adds, single extraction after the chain. (C comp r = batch row r for
// every quad under row-replicated A, so chaining is exact.)
__launch_bounds__(512, 2)
__global__ void k_lstm0(const half_t* __restrict__ xt, const half_t* __restrict__ wch,
                        const float* __restrict__ biasc, const float* __restrict__ whh0,
                        half_t* __restrict__ hs0) {
  __shared__ __align__(16) half_t xs[2][BS][4][80];    // x rows padded 64->80
  __shared__ __align__(16) half_t hr[16][4][144];      // h ring, rows padded 128->144
  const int tid = threadIdx.x;
  const int wave = tid>>6, lane = tid&63, quad = lane>>4, l16 = lane&15;
  const int nm0 = blockIdx.x*4;

  // zero ring slot 15 (read as h[-1] at t=0)
  for (int i=tid; i<4*144; i+=512) (&hr[15][0][0])[i] = (half_t)0.f;

  // Resident weight B-frags: B[k][n] = W[gcol][k]; gcol = nt*128 + wave*16 + l16
  half8 whhF[4][4];
  half8 wcF [4][2];
  float bias[4];
  #pragma unroll
  for (int nt=0; nt<4; nt++) {
    const int gcol = nt*128 + wave*16 + l16;
    #pragma unroll
    for (int kc=0; kc<4; kc++) { whhF[nt][kc] = load_w8(whh0 + gcol*128 + kc*32 + quad*8); pin(whhF[nt][kc]); }
    #pragma unroll
    for (int kc=0; kc<2; kc++) { wcF[nt][kc] = *(const half8*)(wch + gcol*64 + kc*32 + quad*8); pin(wcF[nt][kc]); }
    bias[nt] = biasc[gcol];
  }
  float cst = 0.f;   // lane owns (row=quad, col=wave*16+l16)

  // stage mapping: lane loads 16B = 8 halfs of the block's x
  const int sS = tid>>5;          // step in block 0..15
  const int sR = (tid>>3)&3;      // batch row 0..3
  const int sC = (tid&7)*8;       // col 0..56

  float4 ld = *(const float4*)(xt + ((size_t)sS*NMB + nm0 + sR)*64 + sC);  // block 0
  *(half8*)&xs[0][sS][sR][sC] = __builtin_bit_cast(half8, ld);
  __syncthreads();

  // peel: gxa for t=0 from xs[0][0] (kept as floatx4, bias folded)
  floatx4 gxa[4];
  {
    half8 xA[2];
    #pragma unroll
    for (int kc=0; kc<2; kc++) xA[kc] = *(const half8*)&xs[0][0][l16&3][kc*32 + quad*8];
    #pragma unroll
    for (int nt=0; nt<4; nt++) {
      floatx4 a = {bias[nt],bias[nt],bias[nt],bias[nt]};
      a = __builtin_amdgcn_mfma_f32_16x16x32_f16(xA[0], wcF[nt][0], a, 0,0,0);
      a = __builtin_amdgcn_mfma_f32_16x16x32_f16(xA[1], wcF[nt][1], a, 0,0,0);
      gxa[nt] = a;
    }
  }

  for (int b=0; b<NBLK; b++) {
    const int bs = b*BS, buf = b&1;
    const int cnt = (T_STEPS - bs < BS) ? (T_STEPS - bs) : BS;
    if (b+1 < NBLK) {             // prefetch next block into regs
      int tt = bs + BS + sS; if (tt > 299) tt = 299;
      ld = *(const float4*)(xt + ((size_t)tt*NMB + nm0 + sR)*64 + sC);
    }
    #pragma unroll 2
    for (int s=0; s<cnt; s++) {
      const int t = bs + s;
      if (s == 1 && b+1 < NBLK)   // stage next block (read at s==cnt-1 xproj)
        *(half8*)&xs[buf^1][sS][sR][sC] = __builtin_bit_cast(half8, ld);

      // xproj for step t+1 (latency-tolerant, off the serial chain)
      floatx4 gxn[4];
      {
        const half_t* xrow = (s+1 < cnt) ? &xs[buf][s+1][l16&3][0]
                                         : &xs[buf^1][0][l16&3][0];  // garbage at t==299 (unused)
        half8 xA[2];
        #pragma unroll
        for (int kc=0; kc<2; kc++) xA[kc] = *(const half8*)(xrow + kc*32 + quad*8);
        #pragma unroll
        for (int nt=0; nt<4; nt++) {
          floatx4 a = {bias[nt],bias[nt],bias[nt],bias[nt]};
          a = __builtin_amdgcn_mfma_f32_16x16x32_f16(xA[0], wcF[nt][0], a, 0,0,0);
          a = __builtin_amdgcn_mfma_f32_16x16x32_f16(xA[1], wcF[nt][1], a, 0,0,0);
          gxn[nt] = a;
        }
      }
      // recurrent h-chain, C-initialized from the pipelined xproj accumulator
      half8 hA[4];
      const half_t* hrow = &hr[(t+15)&15][l16&3][0];
      #pragma unroll
      for (int kc=0; kc<4; kc++) hA[kc] = *(const half8*)(hrow + kc*32 + quad*8);
      floatx4 ah[4];
      #pragma unroll
      for (int nt=0; nt<4; nt++) {
        floatx4 a = gxa[nt];
        #pragma unroll
        for (int kc=0; kc<4; kc++)
          a = __builtin_amdgcn_mfma_f32_16x16x32_f16(hA[kc], whhF[nt][kc], a, 0,0,0);
        ah[nt] = a;
      }
      {
        const float gi = ah[0][quad];
        const float gf = ah[1][quad];
        const float gg = ah[2][quad];
        const float go = ah[3][quad];
        cst = fsig(gf)*cst + fsig(gi)*ftanh(gg);
        hr[t&15][quad][wave*16 + l16] = (half_t)(fsig(go)*ftanh(cst));
      }
      #pragma unroll
      for (int nt=0; nt<4; nt++) gxa[nt] = gxn[nt];
      __syncthreads();
    }
    // bulk store this block's h to hs0
    {
      const int hS = tid>>5, hR = (tid>>3)&3, hC = (tid&7)*16;
      if (hS < cnt) {
        half8 a0 = *(const half8*)&hr[(bs+hS)&15][hR][hC];
        half8 a1 = *(const half8*)&hr[(bs+hS)&15][hR][hC+8];
        half_t* dst = hs0 + ((size_t)(bs+hS)*NMB + nm0 + hR)*128 + hC;
        *(half8*)dst = a0; *(half8*)(dst+8) = a1;
      }
    }
    __syncthreads();
  }
}

// ---- KB: layer-1 LSTM (input from hs0, block-staged, xproj pipelined) + FC + softmax
__launch_bounds__(512, 2)
__global__ void k_lstm1(const half_t* __restrict__ hs0, const float* __restrict__ wih1,
                        const float* __restrict__ whh1, const float* __restrict__ bih1,
                        const float* __restrict__ bhh1, const float* __restrict__ fcw,
                        const float* __restrict__ fcb, float* __restrict__ out) {
  __shared__ __align__(16) half_t xs[2][BS][4][144];   // hs0 rows padded 128->144
  __shared__ __align__(16) half_t h2[2][4][144];
  __shared__ float logits_lds[240];
  const int tid = threadIdx.x;
  const int wave = tid>>6, lane = tid&63, quad = lane>>4, l16 = lane&15;
  const int nm0 = blockIdx.x*4;
  for (int i=tid; i<2*4*144; i+=512) (&h2[0][0][0])[i] = (half_t)0.f;

  half8 wxF[4][4], whF[4][4];
  float bias[4];
  #pragma unroll
  for (int nt=0; nt<4; nt++) {
    const int gcol = nt*128 + wave*16 + l16;
    #pragma unroll
    for (int kc=0; kc<4; kc++) {
      wxF[nt][kc] = load_w8(wih1 + gcol*128 + kc*32 + quad*8); pin(wxF[nt][kc]);
      whF[nt][kc] = load_w8(whh1 + gcol*128 + kc*32 + quad*8); pin(whF[nt][kc]);
    }
    bias[nt] = bih1[gcol] + bhh1[gcol];
  }
  float cst = 0.f;

  // stage mapping: lane loads 32B = 16 halfs per block
  const int sS = tid>>5;          // step 0..15
  const int sR = (tid>>3)&3;      // row 0..3
  const int sC = (tid&7)*16;      // col 0..112

  float4 ld0, ld1;
  { const half_t* src = hs0 + ((size_t)sS*NMB + nm0 + sR)*128 + sC;
    ld0 = *(const float4*)src; ld1 = *(const float4*)(src+8); }
  *(half8*)&xs[0][sS][sR][sC]   = __builtin_bit_cast(half8, ld0);
  *(half8*)&xs[0][sS][sR][sC+8] = __builtin_bit_cast(half8, ld1);
  __syncthreads();

  // peel: gxa for t=0 (floatx4, bias folded)
  floatx4 gxa[4];
  {
    half8 xA[4];
    #pragma unroll
    for (int kc=0; kc<4; kc++) xA[kc] = *(const half8*)&xs[0][0][l16&3][kc*32 + quad*8];
    #pragma unroll
    for (int nt=0; nt<4; nt++) {
      floatx4 a = {bias[nt],bias[nt],bias[nt],bias[nt]};
      #pragma unroll
      for (int kc=0; kc<4; kc++)
        a = __builtin_amdgcn_mfma_f32_16x16x32_f16(xA[kc], wxF[nt][kc], a, 0,0,0);
      gxa[nt] = a;
    }
  }

  for (int b=0; b<NBLK; b++) {
    const int bs = b*BS, buf = b&1;
    const int cnt = (T_STEPS - bs < BS) ? (T_STEPS - bs) : BS;
    if (b+1 < NBLK) {
      int tt = bs + BS + sS; if (tt > 299) tt = 299;
      const half_t* src = hs0 + ((size_t)tt*NMB + nm0 + sR)*128 + sC;
      ld0 = *(const float4*)src; ld1 = *(const float4*)(src+8);
    }
    #pragma unroll 2
    for (int s=0; s<cnt; s++) {
      const int t = bs + s;
      if (s == 1 && b+1 < NBLK) {
        *(half8*)&xs[buf^1][sS][sR][sC]   = __builtin_bit_cast(half8, ld0);
        *(half8*)&xs[buf^1][sS][sR][sC+8] = __builtin_bit_cast(half8, ld1);
      }
      // xproj for step t+1 (off the serial chain)
      floatx4 gxn[4];
      {
        const half_t* xrow = (s+1 < cnt) ? &xs[buf][s+1][l16&3][0]
                                         : &xs[buf^1][0][l16&3][0];
        half8 xA[4];
        #pragma unroll
        for (int kc=0; kc<4; kc++) xA[kc] = *(const half8*)(xrow + kc*32 + quad*8);
        #pragma unroll
        for (int nt=0; nt<4; nt++) {
          floatx4 a = {bias[nt],bias[nt],bias[nt],bias[nt]};
          #pragma unroll
          for (int kc=0; kc<4; kc++)
            a = __builtin_amdgcn_mfma_f32_16x16x32_f16(xA[kc], wxF[nt][kc], a, 0,0,0);
          gxn[nt] = a;
        }
      }
      // recurrent h-chain, C-initialized from pipelined xproj accumulator
      half8 hA[4];
      const half_t* hrow = &h2[t&1][l16&3][0];
      #pragma unroll
      for (int kc=0; kc<4; kc++) hA[kc] = *(const half8*)(hrow + kc*32 + quad*8);
      floatx4 ah[4];
      #pragma unroll
      for (int nt=0; nt<4; nt++) {
        floatx4 a = gxa[nt];
        #pragma unroll
        for (int kc=0; kc<4; kc++)
          a = __builtin_amdgcn_mfma_f32_16x16x32_f16(hA[kc], whF[nt][kc], a, 0,0,0);
        ah[nt] = a;
      }
      {
        const float gi = ah[0][quad];
        const float gf = ah[1][quad];
        const float gg = ah[2][quad];
        const float go = ah[3][quad];
        cst = fsig(gf)*cst + fsig(gi)*ftanh(gg);
        h2[(t+1)&1][quad][wave*16 + l16] = (half_t)(fsig(go)*ftanh(cst));
      }
      #pragma unroll
      for (int nt=0; nt<4; nt++) gxa[nt] = gxn[nt];
      __syncthreads();
    }
  }

  // ---- FC (60 classes) + softmax; h1[299] in h2[0] rows 0..3
  if (tid < 240) {
    const int r2 = tid/60, cls = tid%60;
    float s = fcb[cls];
    for (int k2=0; k2<128; k2++) s += (float)h2[0][r2][k2] * fcw[cls*128+k2];
    logits_lds[r2*60+cls] = s;
  }
  __syncthreads();
  if (tid < 4) {
    float m = -1e30f;
    for (int j=0; j<60; j++) m = fmaxf(m, logits_lds[tid*60+j]);
    float s = 0.f;
    for (int j=0; j<60; j++) s += __expf(logits_lds[tid*60+j]-m);
    const float inv = frcp(s);
    for (int j=0; j<60; j++) out[(nm0+tid)*60+j] = __expf(logits_lds[tid*60+j]-m)*inv;
  }
}

extern "C" void kernel_launch(void* const* d_in, const int* in_sizes, int n_in,
                              void* d_out, int out_size, void* d_ws, size_t ws_size,
                              hipStream_t stream) {
  const float* x1      = (const float*)d_in[0];
  const float* cheb_w0 = (const float*)d_in[2];
  const float* cheb_w1 = (const float*)d_in[3];
  const float* cheb_b  = (const float*)d_in[4];
  const float* wih0    = (const float*)d_in[5];
  const float* whh0    = (const float*)d_in[6];
  const float* bih0    = (const float*)d_in[7];
  const float* bhh0    = (const float*)d_in[8];
  const float* wih1    = (const float*)d_in[9];
  const float* whh1    = (const float*)d_in[10];
  const float* bih1    = (const float*)d_in[11];
  const float* bhh1    = (const float*)d_in[12];
  const float* fc_w    = (const float*)d_in[13];
  const float* fc_b    = (const float*)d_in[14];

  char* ws = (char*)d_ws;
  half_t* xt    = (half_t*)(ws + XT_OFF);
  half_t* hs0   = (half_t*)(ws + HS0_OFF);
  half_t* wch   = (half_t*)(ws + WCH_OFF);
  float*  biasc = (float*)(ws + BC_OFF);

  k_prep <<<dim3(1),     dim3(512), 0, stream>>>(cheb_w0, cheb_w1, cheb_b, wih0, bih0, bhh0, wch, biasc);
  k_xpose<<<dim3(27000), dim3(256), 0, stream>>>(x1, xt);
  k_lstm0<<<dim3(256),   dim3(512), 0, stream>>>(xt, wch, biasc, whh0, hs0);
  k_lstm1<<<dim3(256),   dim3(512), 0, stream>>>(hs0, wih1, whh1, bih1, bhh1, fc_w, fc_b, (float*)d_out);
}